// Round 15
// baseline (218.693 us; speedup 1.0000x reference)
//
#include <hip/hip_runtime.h>
#include <math.h>

// Round 15: non-flash cleanup. (1) flash_combine deleted — gemm_proj stages A
// directly from the 4 bf16 O-partials (fp32 sum x invl from LDS; same rounding
// path as before). Kills a kernel + 31 MB Y round-trip. (2) 3 convert launches
// merged into 1. flash_partial & gemm_qkv byte-identical to R14 (known good).

typedef __bf16 bf16;
typedef __bf16 bf16x4 __attribute__((ext_vector_type(4)));
typedef __bf16 bf16x8 __attribute__((ext_vector_type(8)));
typedef float  f32x4  __attribute__((ext_vector_type(4)));

#define MFMA_BF16(a, b, c) __builtin_amdgcn_mfma_f32_16x16x32_bf16((a), (b), (c), 0, 0, 0)

#define SEQ  4096
#define NH   12
#define HD   64
#define DM   768
#define NQKV 2304
#define NPART 4
#define ATTN_SCALE 0.12f
#define RMS_EPS 1.1920928955078125e-07f
#define NX (SEQ * DM)      // 3,145,728
#define NW (NQKV * DM)     // 1,769,472
#define NP (DM * DM)       //   589,824

// ---------------------------------------------------------------------------
// One launch converts all three fp32 inputs to bf16 (region per block; all
// region sizes are multiples of 2048 so branches are block-uniform).
// ---------------------------------------------------------------------------
__global__ __launch_bounds__(256) void convert_all(
    const float* __restrict__ x, const float* __restrict__ w1,
    const float* __restrict__ w2, bf16* __restrict__ xb,
    bf16* __restrict__ wb1, bf16* __restrict__ wb2)
{
  const int gi = (blockIdx.x * 256 + threadIdx.x) * 8;
  const float* src; bf16* dst; int off;
  if (gi < NX)            { src = x;  dst = xb;  off = gi; }
  else if (gi < NX + NW)  { src = w1; dst = wb1; off = gi - NX; }
  else                    { src = w2; dst = wb2; off = gi - NX - NW; }
  f32x4 a = *(const f32x4*)(src + off);
  f32x4 b = *(const f32x4*)(src + off + 4);
  bf16x8 o;
#pragma unroll
  for (int j = 0; j < 4; j++) { o[j] = (bf16)a[j]; o[j + 4] = (bf16)b[j]; }
  *(bf16x8*)(dst + off) = o;
}

// ---------------------------------------------------------------------------
// 128x128-tile GEMM core (BK=32, 4 waves in 2x2 quadrants of 64x64).
// ---------------------------------------------------------------------------
__device__ __forceinline__ void gemm128_core(
    const bf16* __restrict__ A, const bf16* __restrict__ B,
    int m0, int n0, bf16 (*As)[40], bf16 (*Bs)[40], f32x4 acc[4][4])
{
  const int tid = threadIdx.x;
  const int lane = tid & 63, w = tid >> 6;
  const int c16 = lane & 15, q4 = lane >> 4;
  const int mo = (w & 1) * 64, no = (w >> 1) * 64;
  const int srow = tid >> 2, scol = (tid & 3) * 8;
  const f32x4 vzero = {0.f, 0.f, 0.f, 0.f};
#pragma unroll
  for (int i = 0; i < 4; i++)
#pragma unroll
    for (int j = 0; j < 4; j++) acc[i][j] = vzero;

  for (int k0 = 0; k0 < DM; k0 += 32) {
#pragma unroll
    for (int ps = 0; ps < 2; ps++) {
      const int r = srow + ps * 64;
      *(bf16x8*)&As[r][scol] = *(const bf16x8*)&A[(m0 + r) * DM + k0 + scol];
      *(bf16x8*)&Bs[r][scol] = *(const bf16x8*)&B[(n0 + r) * DM + k0 + scol];
    }
    __syncthreads();
    bf16x8 ar[4], br[4];
#pragma unroll
    for (int mq = 0; mq < 4; mq++)
      ar[mq] = *(const bf16x8*)&As[mo + mq * 16 + c16][q4 * 8];
#pragma unroll
    for (int nq = 0; nq < 4; nq++)
      br[nq] = *(const bf16x8*)&Bs[no + nq * 16 + c16][q4 * 8];
#pragma unroll
    for (int mq = 0; mq < 4; mq++)
#pragma unroll
      for (int nq = 0; nq < 4; nq++)
        acc[mq][nq] = MFMA_BF16(ar[mq], br[nq], acc[mq][nq]);
    __syncthreads();
  }
}

// QKV GEMM with FUSED norm+rope epilogue for Q/K (V written transposed raw).
__global__ __launch_bounds__(256) void gemm_qkv(
    const bf16* __restrict__ A, const bf16* __restrict__ B,
    bf16* __restrict__ Qb, bf16* __restrict__ Kb, bf16* __restrict__ Vt)
{
  __shared__ bf16 As[128][40];
  __shared__ bf16 Bs[128][40];
  const int m0 = blockIdx.x * 128, n0 = blockIdx.y * 128;
  f32x4 acc[4][4];
  gemm128_core(A, B, m0, n0, As, Bs, acc);

  const int lane = threadIdx.x & 63, w = threadIdx.x >> 6;
  const int c16 = lane & 15, q4 = lane >> 4;
  const int mo = (w & 1) * 64, no = (w >> 1) * 64;
  const int kidx = blockIdx.y / 6;
  const int rr0 = (n0 - kidx * DM) + no;     // multiple of 64: one full head
  const int h = rr0 >> 6;

  if (kidx == 2) {
#pragma unroll
    for (int nq = 0; nq < 4; nq++) {
      const int d = nq * 16 + c16;
#pragma unroll
      for (int mq = 0; mq < 4; mq++) {
        const int mb = m0 + mo + mq * 16 + q4 * 4;
#pragma unroll
        for (int rg = 0; rg < 4; rg++)
          Vt[((h * HD) + d) * SEQ + mb + rg] = (bf16)acc[mq][nq][rg];
      }
    }
  } else {
    bf16* dst = kidx ? Kb : Qb;
    const float scale = kidx ? 1.0f : ATTN_SCALE;
    const float fr = exp2f(-10.0f * (float)c16 * (1.0f / 15.0f));
#pragma unroll
    for (int mq = 0; mq < 4; mq++) {
#pragma unroll
      for (int rg = 0; rg < 4; rg++) {
        const int m = m0 + mo + mq * 16 + q4 * 4 + rg;
        const float x0 = acc[mq][0][rg], x1 = acc[mq][1][rg];
        const float x2 = acc[mq][2][rg], x3 = acc[mq][3][rg];
        float ss = x0 * x0 + x1 * x1 + x2 * x2 + x3 * x3;
        ss += __shfl_xor(ss, 1, 64);
        ss += __shfl_xor(ss, 2, 64);
        ss += __shfl_xor(ss, 4, 64);
        ss += __shfl_xor(ss, 8, 64);
        const float rinv = rsqrtf(ss * (1.0f / 64.0f) + RMS_EPS) * scale;
        const float xn0 = x0 * rinv, xn1 = x1 * rinv;
        const float xn2 = x2 * rinv, xn3 = x3 * rinv;
        float sn, cs;
        __sincosf((float)m * fr, &sn, &cs);
        const float y0 = xn0 * cs + xn2 * sn;
        const float y2 = xn2 * cs - xn0 * sn;
        bf16* rp = dst + (size_t)(h * SEQ + m) * HD + c16;
        rp[0]  = (bf16)y0;
        rp[16] = (bf16)xn1;
        rp[32] = (bf16)y2;
        rp[48] = (bf16)xn3;
      }
    }
  }
}

// ---------------------------------------------------------------------------
// Projection GEMM with FUSED split-K combine: A-tile staged directly from the
// 4 bf16 O-partials (fp32 sum x invl), B = c_proj_w bf16, fp32 store to out.
// m-tile (128 rows) = exactly one qi; invl[h][t] precomputed in LDS (6 KB).
// ---------------------------------------------------------------------------
__global__ __launch_bounds__(256) void gemm_proj(
    const bf16* __restrict__ Opart, const float* __restrict__ Lpart,
    const bf16* __restrict__ B, float* __restrict__ C)
{
  __shared__ bf16 As[128][40];
  __shared__ bf16 Bs[128][40];
  __shared__ float invl[NH][128];
  const int m0 = blockIdx.x * 128, n0 = blockIdx.y * 128;
  const int qi = m0 >> 7;
  const int tid = threadIdx.x;

  for (int i = tid; i < NH * 128; i += 256) {
    const int hh = i >> 7, t = i & 127;
    const int u0 = (hh * 32 + qi) * NPART;
    float s = 0.f;
#pragma unroll
    for (int p = 0; p < NPART; p++) s += Lpart[(u0 + p) * 128 + t];
    invl[hh][t] = 1.0f / s;
  }
  __syncthreads();

  const int lane = tid & 63, w = tid >> 6;
  const int c16 = lane & 15, q4 = lane >> 4;
  const int mo = (w & 1) * 64, no = (w >> 1) * 64;
  const int srow = tid >> 2, scol = (tid & 3) * 8;
  const f32x4 vzero = {0.f, 0.f, 0.f, 0.f};
  f32x4 acc[4][4];
#pragma unroll
  for (int i = 0; i < 4; i++)
#pragma unroll
    for (int j = 0; j < 4; j++) acc[i][j] = vzero;

  for (int k0 = 0; k0 < DM; k0 += 32) {
    const int hh = k0 >> 6;
    const int dcol = (k0 & 63) + scol;             // 0..63
    const size_t ub = (size_t)((hh * 32 + qi) * NPART) * 8192;
#pragma unroll
    for (int ps = 0; ps < 2; ps++) {
      const int r = srow + ps * 64;
      // A: combine 4 partials inline (same rounding path as old combine+Y)
      const size_t ob = ub + (size_t)r * 64 + dcol;
      bf16x8 a0 = *(const bf16x8*)&Opart[ob];
      bf16x8 a1 = *(const bf16x8*)&Opart[ob + 8192];
      bf16x8 a2 = *(const bf16x8*)&Opart[ob + 16384];
      bf16x8 a3 = *(const bf16x8*)&Opart[ob + 24576];
      const float iv = invl[hh][r];
      bf16x8 o;
#pragma unroll
      for (int e = 0; e < 8; e++)
        o[e] = (bf16)(((float)a0[e] + (float)a1[e] + (float)a2[e] + (float)a3[e]) * iv);
      *(bf16x8*)&As[r][scol] = o;
      *(bf16x8*)&Bs[r][scol] = *(const bf16x8*)&B[(n0 + r) * DM + k0 + scol];
    }
    __syncthreads();
    bf16x8 ar[4], br[4];
#pragma unroll
    for (int mq = 0; mq < 4; mq++)
      ar[mq] = *(const bf16x8*)&As[mo + mq * 16 + c16][q4 * 8];
#pragma unroll
    for (int nq = 0; nq < 4; nq++)
      br[nq] = *(const bf16x8*)&Bs[no + nq * 16 + c16][q4 * 8];
#pragma unroll
    for (int mq = 0; mq < 4; mq++)
#pragma unroll
      for (int nq = 0; nq < 4; nq++)
        acc[mq][nq] = MFMA_BF16(ar[mq], br[nq], acc[mq][nq]);
    __syncthreads();
  }
#pragma unroll
  for (int nq = 0; nq < 4; nq++) {
    const int n = n0 + no + nq * 16 + c16;
#pragma unroll
    for (int mq = 0; mq < 4; mq++) {
      const int mb = m0 + mo + mq * 16 + q4 * 4;
#pragma unroll
      for (int rg = 0; rg < 4; rg++)
        C[(size_t)(mb + rg) * DM + n] = acc[mq][nq][rg];
    }
  }
}

// ---------------------------------------------------------------------------
// Flash partial, BM=128, S^T orientation (R12/R14 known-good, unchanged).
// ---------------------------------------------------------------------------
__global__ __launch_bounds__(256) void flash_partial(
    const bf16* __restrict__ Qb, const bf16* __restrict__ Kb,
    const bf16* __restrict__ Vt, bf16* __restrict__ Opart,
    float* __restrict__ Lpart)
{
  __shared__ bf16 Ks[64][72];
  __shared__ bf16 Vts[64][72];
  __shared__ bf16 Pst[4][32][68];                 // [wave][q][s], stride 68
  const int h = blockIdx.y, p = blockIdx.z;
  const int qi = 31 - (int)blockIdx.x;            // LPT: heavy blocks first
  const int q0 = qi * 128;
  const int tid = threadIdx.x;
  const int lane = tid & 63, w = tid >> 6;
  const int c16 = lane & 15, q4 = lane >> 4;
  const int sr = tid >> 3, sc8 = (tid & 7) * 8;

  bf16x8 aq[2][2];
#pragma unroll
  for (int f = 0; f < 2; f++) {
    const int tq = q0 + w * 32 + f * 16 + c16;
    aq[f][0] = *(const bf16x8*)&Qb[((h * SEQ) + tq) * HD + q4 * 8];
    aq[f][1] = *(const bf16x8*)&Qb[((h * SEQ) + tq) * HD + 32 + q4 * 8];
  }
  const int qg[2] = { q0 + w * 32 + c16, q0 + w * 32 + 16 + c16 };

  const f32x4 vzero = {0.f, 0.f, 0.f, 0.f};
  f32x4 O[2][4];
  float l_f[2] = {0.f, 0.f};
#pragma unroll
  for (int f = 0; f < 2; f++)
#pragma unroll
    for (int j = 0; j < 4; j++) O[f][j] = vzero;

  const bf16* Kbase = Kb + (size_t)h * SEQ * HD;
  const bf16* Vbase = Vt + (size_t)h * HD * SEQ;

  const int sEnd = q0 + 64;
  const int sBeg = p * 64;
  if (sBeg <= sEnd) {
    bf16x8 kr0 = *(const bf16x8*)&Kbase[(sBeg + sr) * HD + sc8];
    bf16x8 kr1 = *(const bf16x8*)&Kbase[(sBeg + sr + 32) * HD + sc8];
    bf16x8 vr0 = *(const bf16x8*)&Vbase[sr * SEQ + sBeg + sc8];
    bf16x8 vr1 = *(const bf16x8*)&Vbase[(sr + 32) * SEQ + sBeg + sc8];

    for (int s0 = sBeg; s0 <= sEnd; s0 += NPART * 64) {
      __syncthreads();
      *(bf16x8*)&Ks[sr][sc8]       = kr0;
      *(bf16x8*)&Ks[sr + 32][sc8]  = kr1;
      *(bf16x8*)&Vts[sr][sc8]      = vr0;
      *(bf16x8*)&Vts[sr + 32][sc8] = vr1;
      __syncthreads();

      const int snext = s0 + NPART * 64;
      if (snext <= sEnd) {
        kr0 = *(const bf16x8*)&Kbase[(snext + sr) * HD + sc8];
        kr1 = *(const bf16x8*)&Kbase[(snext + sr + 32) * HD + sc8];
        vr0 = *(const bf16x8*)&Vbase[sr * SEQ + snext + sc8];
        vr1 = *(const bf16x8*)&Vbase[(sr + 32) * SEQ + snext + sc8];
      }

      bf16x8 kf0[4], kf1[4];
#pragma unroll
      for (int nt = 0; nt < 4; nt++) {
        kf0[nt] = *(const bf16x8*)&Ks[nt * 16 + c16][q4 * 8];
        kf1[nt] = *(const bf16x8*)&Ks[nt * 16 + c16][32 + q4 * 8];
      }
#pragma unroll
      for (int f = 0; f < 2; f++) {
        f32x4 S[4];
#pragma unroll
        for (int nt = 0; nt < 4; nt++) {
          f32x4 z = vzero;
          z = MFMA_BF16(kf0[nt], aq[f][0], z);
          z = MFMA_BF16(kf1[nt], aq[f][1], z);
          S[nt] = z;
        }
        float lf = l_f[f];
#pragma unroll
        for (int nt = 0; nt < 4; nt++) {
#pragma unroll
          for (int rg = 0; rg < 4; rg++) {
            const int s_g = s0 + nt * 16 + q4 * 4 + rg;
            const float pv = (s_g > qg[f]) ? 0.f : __expf(S[nt][rg]);
            S[nt][rg] = pv;
            lf += pv;
          }
          bf16x4 pk = { (bf16)S[nt][0], (bf16)S[nt][1], (bf16)S[nt][2], (bf16)S[nt][3] };
          *(bf16x4*)&Pst[w][f * 16 + c16][nt * 16 + q4 * 4] = pk;
        }
        l_f[f] = lf;
      }
      bf16x8 ap[2][2];
#pragma unroll
      for (int f = 0; f < 2; f++) {
        ap[f][0] = *(const bf16x8*)&Pst[w][f * 16 + c16][q4 * 8];
        ap[f][1] = *(const bf16x8*)&Pst[w][f * 16 + c16][32 + q4 * 8];
      }
#pragma unroll
      for (int dt = 0; dt < 4; dt++) {
        bf16x8 bv0 = *(const bf16x8*)&Vts[dt * 16 + c16][q4 * 8];
        bf16x8 bv1 = *(const bf16x8*)&Vts[dt * 16 + c16][32 + q4 * 8];
#pragma unroll
        for (int f = 0; f < 2; f++) {
          O[f][dt] = MFMA_BF16(ap[f][0], bv0, O[f][dt]);
          O[f][dt] = MFMA_BF16(ap[f][1], bv1, O[f][dt]);
        }
      }
    }
  }
#pragma unroll
  for (int f = 0; f < 2; f++) {
    float l = l_f[f];
    l += __shfl_xor(l, 16, 64);
    l += __shfl_xor(l, 32, 64);
    l_f[f] = l;
  }
  const int u = ((h * 32 + qi) * NPART + p);
  bf16* Op = Opart + (size_t)u * 8192;            // 128 x 64
#pragma unroll
  for (int f = 0; f < 2; f++)
#pragma unroll
    for (int dt = 0; dt < 4; dt++)
#pragma unroll
      for (int rg = 0; rg < 4; rg++)
        Op[(w * 32 + f * 16 + q4 * 4 + rg) * 64 + dt * 16 + c16] = (bf16)O[f][dt][rg];
  if (lane < 16) {                                // q4 == 0 -> one writer per row
#pragma unroll
    for (int f = 0; f < 2; f++)
      Lpart[u * 128 + w * 32 + f * 16 + c16] = l_f[f];
  }
}

// ---------------------------------------------------------------------------
extern "C" void kernel_launch(void* const* d_in, const int* in_sizes, int n_in,
                              void* d_out, int out_size, void* d_ws, size_t ws_size,
                              hipStream_t stream)
{
  (void)in_sizes; (void)n_in; (void)out_size; (void)ws_size;
  const float* x      = (const float*)d_in[0];
  const float* qkvw   = (const float*)d_in[1];
  const float* cprojw = (const float*)d_in[2];
  float* outp = (float*)d_out;

  char* ws = (char*)d_ws;
  bf16*  xb    = (bf16*)(ws);                       // 6,291,456
  bf16*  wqkv  = (bf16*)(ws + 6291456);             // 3,538,944
  bf16*  wproj = (bf16*)(ws + 9830400);             // 1,179,648
  bf16*  Q     = (bf16*)(ws + 11010048);            // 6,291,456
  bf16*  K     = (bf16*)(ws + 17301504);            // 6,291,456
  bf16*  Vt    = (bf16*)(ws + 23592960);            // 6,291,456
  bf16*  Opart = (bf16*)(ws + 29884416);            // 25,165,824 (1536 x 8192 bf16)
  float* Lpart = (float*)(ws + 55050240);           //    786,432  (total 55.8 MB)

  convert_all  <<<dim3((NX + NW + NP) / 2048),   256, 0, stream>>>(x, qkvw, cprojw, xb, wqkv, wproj);
  gemm_qkv     <<<dim3(SEQ / 128, NQKV / 128),   256, 0, stream>>>(xb, wqkv, Q, K, Vt);
  flash_partial<<<dim3(SEQ / 128, NH, NPART),    256, 0, stream>>>(Q, K, Vt, Opart, Lpart);
  gemm_proj    <<<dim3(SEQ / 128, DM / 128),     256, 0, stream>>>(Opart, Lpart, wproj, outp);
}

// Round 16
// 218.555 us; speedup vs baseline: 1.0006x; 1.0006x over previous
//
#include <hip/hip_runtime.h>
#include <math.h>

// Round 16: gemm_qkv epilogue store fix (single variable vs R15).
// Q/K stored with PERMUTED d (d' = c16*4 + {0..3}) — same permutation for
// both, so QK^T is invariant; rotary/RMS applied pre-store. One bf16x4 8B
// coalesced store replaces 4 scalar 2B stride-32B stores. V rg-quad
// vectorized to bf16x4. flash/gemm_proj/convert byte-identical to R15.

typedef __bf16 bf16;
typedef __bf16 bf16x4 __attribute__((ext_vector_type(4)));
typedef __bf16 bf16x8 __attribute__((ext_vector_type(8)));
typedef float  f32x4  __attribute__((ext_vector_type(4)));

#define MFMA_BF16(a, b, c) __builtin_amdgcn_mfma_f32_16x16x32_bf16((a), (b), (c), 0, 0, 0)

#define SEQ  4096
#define NH   12
#define HD   64
#define DM   768
#define NQKV 2304
#define NPART 4
#define ATTN_SCALE 0.12f
#define RMS_EPS 1.1920928955078125e-07f
#define NX (SEQ * DM)
#define NW (NQKV * DM)
#define NP (DM * DM)

// ---------------------------------------------------------------------------
__global__ __launch_bounds__(256) void convert_all(
    const float* __restrict__ x, const float* __restrict__ w1,
    const float* __restrict__ w2, bf16* __restrict__ xb,
    bf16* __restrict__ wb1, bf16* __restrict__ wb2)
{
  const int gi = (blockIdx.x * 256 + threadIdx.x) * 8;
  const float* src; bf16* dst; int off;
  if (gi < NX)            { src = x;  dst = xb;  off = gi; }
  else if (gi < NX + NW)  { src = w1; dst = wb1; off = gi - NX; }
  else                    { src = w2; dst = wb2; off = gi - NX - NW; }
  f32x4 a = *(const f32x4*)(src + off);
  f32x4 b = *(const f32x4*)(src + off + 4);
  bf16x8 o;
#pragma unroll
  for (int j = 0; j < 4; j++) { o[j] = (bf16)a[j]; o[j + 4] = (bf16)b[j]; }
  *(bf16x8*)(dst + off) = o;
}

// ---------------------------------------------------------------------------
// 128x128-tile GEMM core (BK=32, 4 waves in 2x2 quadrants of 64x64).
// ---------------------------------------------------------------------------
__device__ __forceinline__ void gemm128_core(
    const bf16* __restrict__ A, const bf16* __restrict__ B,
    int m0, int n0, bf16 (*As)[40], bf16 (*Bs)[40], f32x4 acc[4][4])
{
  const int tid = threadIdx.x;
  const int lane = tid & 63, w = tid >> 6;
  const int c16 = lane & 15, q4 = lane >> 4;
  const int mo = (w & 1) * 64, no = (w >> 1) * 64;
  const int srow = tid >> 2, scol = (tid & 3) * 8;
  const f32x4 vzero = {0.f, 0.f, 0.f, 0.f};
#pragma unroll
  for (int i = 0; i < 4; i++)
#pragma unroll
    for (int j = 0; j < 4; j++) acc[i][j] = vzero;

  for (int k0 = 0; k0 < DM; k0 += 32) {
#pragma unroll
    for (int ps = 0; ps < 2; ps++) {
      const int r = srow + ps * 64;
      *(bf16x8*)&As[r][scol] = *(const bf16x8*)&A[(m0 + r) * DM + k0 + scol];
      *(bf16x8*)&Bs[r][scol] = *(const bf16x8*)&B[(n0 + r) * DM + k0 + scol];
    }
    __syncthreads();
    bf16x8 ar[4], br[4];
#pragma unroll
    for (int mq = 0; mq < 4; mq++)
      ar[mq] = *(const bf16x8*)&As[mo + mq * 16 + c16][q4 * 8];
#pragma unroll
    for (int nq = 0; nq < 4; nq++)
      br[nq] = *(const bf16x8*)&Bs[no + nq * 16 + c16][q4 * 8];
#pragma unroll
    for (int mq = 0; mq < 4; mq++)
#pragma unroll
      for (int nq = 0; nq < 4; nq++)
        acc[mq][nq] = MFMA_BF16(ar[mq], br[nq], acc[mq][nq]);
    __syncthreads();
  }
}

// QKV GEMM, fused norm+rope epilogue. Q/K stored with permuted d (coalesced
// bf16x4); V transposed, rg-quad vectorized.
__global__ __launch_bounds__(256) void gemm_qkv(
    const bf16* __restrict__ A, const bf16* __restrict__ B,
    bf16* __restrict__ Qb, bf16* __restrict__ Kb, bf16* __restrict__ Vt)
{
  __shared__ bf16 As[128][40];
  __shared__ bf16 Bs[128][40];
  const int m0 = blockIdx.x * 128, n0 = blockIdx.y * 128;
  f32x4 acc[4][4];
  gemm128_core(A, B, m0, n0, As, Bs, acc);

  const int lane = threadIdx.x & 63, w = threadIdx.x >> 6;
  const int c16 = lane & 15, q4 = lane >> 4;
  const int mo = (w & 1) * 64, no = (w >> 1) * 64;
  const int kidx = blockIdx.y / 6;
  const int rr0 = (n0 - kidx * DM) + no;     // multiple of 64: one full head
  const int h = rr0 >> 6;

  if (kidx == 2) {
#pragma unroll
    for (int nq = 0; nq < 4; nq++) {
      const int d = nq * 16 + c16;
#pragma unroll
      for (int mq = 0; mq < 4; mq++) {
        const int mb = m0 + mo + mq * 16 + q4 * 4;
        bf16x4 pv = { (bf16)acc[mq][nq][0], (bf16)acc[mq][nq][1],
                      (bf16)acc[mq][nq][2], (bf16)acc[mq][nq][3] };
        *(bf16x4*)&Vt[((h * HD) + d) * SEQ + mb] = pv;
      }
    }
  } else {
    bf16* dst = kidx ? Kb : Qb;
    const float scale = kidx ? 1.0f : ATTN_SCALE;
    const float fr = exp2f(-10.0f * (float)c16 * (1.0f / 15.0f));
#pragma unroll
    for (int mq = 0; mq < 4; mq++) {
#pragma unroll
      for (int rg = 0; rg < 4; rg++) {
        const int m = m0 + mo + mq * 16 + q4 * 4 + rg;
        const float x0 = acc[mq][0][rg], x1 = acc[mq][1][rg];
        const float x2 = acc[mq][2][rg], x3 = acc[mq][3][rg];
        float ss = x0 * x0 + x1 * x1 + x2 * x2 + x3 * x3;
        ss += __shfl_xor(ss, 1, 64);
        ss += __shfl_xor(ss, 2, 64);
        ss += __shfl_xor(ss, 4, 64);
        ss += __shfl_xor(ss, 8, 64);
        const float rinv = rsqrtf(ss * (1.0f / 64.0f) + RMS_EPS) * scale;
        const float xn0 = x0 * rinv, xn1 = x1 * rinv;
        const float xn2 = x2 * rinv, xn3 = x3 * rinv;
        float sn, cs;
        __sincosf((float)m * fr, &sn, &cs);
        const float y0 = xn0 * cs + xn2 * sn;
        const float y2 = xn2 * cs - xn0 * sn;
        // permuted d: lane's 4 values stored contiguously at d' = c16*4
        bf16x4 pk = { (bf16)y0, (bf16)xn1, (bf16)y2, (bf16)xn3 };
        *(bf16x4*)&dst[(size_t)(h * SEQ + m) * HD + c16 * 4] = pk;
      }
    }
  }
}

// ---------------------------------------------------------------------------
// Projection GEMM with fused split-K combine (unchanged from R15).
// ---------------------------------------------------------------------------
__global__ __launch_bounds__(256) void gemm_proj(
    const bf16* __restrict__ Opart, const float* __restrict__ Lpart,
    const bf16* __restrict__ B, float* __restrict__ C)
{
  __shared__ bf16 As[128][40];
  __shared__ bf16 Bs[128][40];
  __shared__ float invl[NH][128];
  const int m0 = blockIdx.x * 128, n0 = blockIdx.y * 128;
  const int qi = m0 >> 7;
  const int tid = threadIdx.x;

  for (int i = tid; i < NH * 128; i += 256) {
    const int hh = i >> 7, t = i & 127;
    const int u0 = (hh * 32 + qi) * NPART;
    float s = 0.f;
#pragma unroll
    for (int p = 0; p < NPART; p++) s += Lpart[(u0 + p) * 128 + t];
    invl[hh][t] = 1.0f / s;
  }
  __syncthreads();

  const int lane = tid & 63, w = tid >> 6;
  const int c16 = lane & 15, q4 = lane >> 4;
  const int mo = (w & 1) * 64, no = (w >> 1) * 64;
  const int srow = tid >> 2, scol = (tid & 3) * 8;
  const f32x4 vzero = {0.f, 0.f, 0.f, 0.f};
  f32x4 acc[4][4];
#pragma unroll
  for (int i = 0; i < 4; i++)
#pragma unroll
    for (int j = 0; j < 4; j++) acc[i][j] = vzero;

  for (int k0 = 0; k0 < DM; k0 += 32) {
    const int hh = k0 >> 6;
    const int dcol = (k0 & 63) + scol;
    const size_t ub = (size_t)((hh * 32 + qi) * NPART) * 8192;
#pragma unroll
    for (int ps = 0; ps < 2; ps++) {
      const int r = srow + ps * 64;
      const size_t ob = ub + (size_t)r * 64 + dcol;
      bf16x8 a0 = *(const bf16x8*)&Opart[ob];
      bf16x8 a1 = *(const bf16x8*)&Opart[ob + 8192];
      bf16x8 a2 = *(const bf16x8*)&Opart[ob + 16384];
      bf16x8 a3 = *(const bf16x8*)&Opart[ob + 24576];
      const float iv = invl[hh][r];
      bf16x8 o;
#pragma unroll
      for (int e = 0; e < 8; e++)
        o[e] = (bf16)(((float)a0[e] + (float)a1[e] + (float)a2[e] + (float)a3[e]) * iv);
      *(bf16x8*)&As[r][scol] = o;
      *(bf16x8*)&Bs[r][scol] = *(const bf16x8*)&B[(n0 + r) * DM + k0 + scol];
    }
    __syncthreads();
    bf16x8 ar[4], br[4];
#pragma unroll
    for (int mq = 0; mq < 4; mq++)
      ar[mq] = *(const bf16x8*)&As[mo + mq * 16 + c16][q4 * 8];
#pragma unroll
    for (int nq = 0; nq < 4; nq++)
      br[nq] = *(const bf16x8*)&Bs[no + nq * 16 + c16][q4 * 8];
#pragma unroll
    for (int mq = 0; mq < 4; mq++)
#pragma unroll
      for (int nq = 0; nq < 4; nq++)
        acc[mq][nq] = MFMA_BF16(ar[mq], br[nq], acc[mq][nq]);
    __syncthreads();
  }
#pragma unroll
  for (int nq = 0; nq < 4; nq++) {
    const int n = n0 + no + nq * 16 + c16;
#pragma unroll
    for (int mq = 0; mq < 4; mq++) {
      const int mb = m0 + mo + mq * 16 + q4 * 4;
#pragma unroll
      for (int rg = 0; rg < 4; rg++)
        C[(size_t)(mb + rg) * DM + n] = acc[mq][nq][rg];
    }
  }
}

// ---------------------------------------------------------------------------
// Flash partial, BM=128, S^T orientation (R12/R14 known-good, unchanged).
// Q/K d-permutation is transparent here (linear reads, both permuted alike).
// ---------------------------------------------------------------------------
__global__ __launch_bounds__(256) void flash_partial(
    const bf16* __restrict__ Qb, const bf16* __restrict__ Kb,
    const bf16* __restrict__ Vt, bf16* __restrict__ Opart,
    float* __restrict__ Lpart)
{
  __shared__ bf16 Ks[64][72];
  __shared__ bf16 Vts[64][72];
  __shared__ bf16 Pst[4][32][68];
  const int h = blockIdx.y, p = blockIdx.z;
  const int qi = 31 - (int)blockIdx.x;
  const int q0 = qi * 128;
  const int tid = threadIdx.x;
  const int lane = tid & 63, w = tid >> 6;
  const int c16 = lane & 15, q4 = lane >> 4;
  const int sr = tid >> 3, sc8 = (tid & 7) * 8;

  bf16x8 aq[2][2];
#pragma unroll
  for (int f = 0; f < 2; f++) {
    const int tq = q0 + w * 32 + f * 16 + c16;
    aq[f][0] = *(const bf16x8*)&Qb[((h * SEQ) + tq) * HD + q4 * 8];
    aq[f][1] = *(const bf16x8*)&Qb[((h * SEQ) + tq) * HD + 32 + q4 * 8];
  }
  const int qg[2] = { q0 + w * 32 + c16, q0 + w * 32 + 16 + c16 };

  const f32x4 vzero = {0.f, 0.f, 0.f, 0.f};
  f32x4 O[2][4];
  float l_f[2] = {0.f, 0.f};
#pragma unroll
  for (int f = 0; f < 2; f++)
#pragma unroll
    for (int j = 0; j < 4; j++) O[f][j] = vzero;

  const bf16* Kbase = Kb + (size_t)h * SEQ * HD;
  const bf16* Vbase = Vt + (size_t)h * HD * SEQ;

  const int sEnd = q0 + 64;
  const int sBeg = p * 64;
  if (sBeg <= sEnd) {
    bf16x8 kr0 = *(const bf16x8*)&Kbase[(sBeg + sr) * HD + sc8];
    bf16x8 kr1 = *(const bf16x8*)&Kbase[(sBeg + sr + 32) * HD + sc8];
    bf16x8 vr0 = *(const bf16x8*)&Vbase[sr * SEQ + sBeg + sc8];
    bf16x8 vr1 = *(const bf16x8*)&Vbase[(sr + 32) * SEQ + sBeg + sc8];

    for (int s0 = sBeg; s0 <= sEnd; s0 += NPART * 64) {
      __syncthreads();
      *(bf16x8*)&Ks[sr][sc8]       = kr0;
      *(bf16x8*)&Ks[sr + 32][sc8]  = kr1;
      *(bf16x8*)&Vts[sr][sc8]      = vr0;
      *(bf16x8*)&Vts[sr + 32][sc8] = vr1;
      __syncthreads();

      const int snext = s0 + NPART * 64;
      if (snext <= sEnd) {
        kr0 = *(const bf16x8*)&Kbase[(snext + sr) * HD + sc8];
        kr1 = *(const bf16x8*)&Kbase[(snext + sr + 32) * HD + sc8];
        vr0 = *(const bf16x8*)&Vbase[sr * SEQ + snext + sc8];
        vr1 = *(const bf16x8*)&Vbase[(sr + 32) * SEQ + snext + sc8];
      }

      bf16x8 kf0[4], kf1[4];
#pragma unroll
      for (int nt = 0; nt < 4; nt++) {
        kf0[nt] = *(const bf16x8*)&Ks[nt * 16 + c16][q4 * 8];
        kf1[nt] = *(const bf16x8*)&Ks[nt * 16 + c16][32 + q4 * 8];
      }
#pragma unroll
      for (int f = 0; f < 2; f++) {
        f32x4 S[4];
#pragma unroll
        for (int nt = 0; nt < 4; nt++) {
          f32x4 z = vzero;
          z = MFMA_BF16(kf0[nt], aq[f][0], z);
          z = MFMA_BF16(kf1[nt], aq[f][1], z);
          S[nt] = z;
        }
        float lf = l_f[f];
#pragma unroll
        for (int nt = 0; nt < 4; nt++) {
#pragma unroll
          for (int rg = 0; rg < 4; rg++) {
            const int s_g = s0 + nt * 16 + q4 * 4 + rg;
            const float pv = (s_g > qg[f]) ? 0.f : __expf(S[nt][rg]);
            S[nt][rg] = pv;
            lf += pv;
          }
          bf16x4 pk = { (bf16)S[nt][0], (bf16)S[nt][1], (bf16)S[nt][2], (bf16)S[nt][3] };
          *(bf16x4*)&Pst[w][f * 16 + c16][nt * 16 + q4 * 4] = pk;
        }
        l_f[f] = lf;
      }
      bf16x8 ap[2][2];
#pragma unroll
      for (int f = 0; f < 2; f++) {
        ap[f][0] = *(const bf16x8*)&Pst[w][f * 16 + c16][q4 * 8];
        ap[f][1] = *(const bf16x8*)&Pst[w][f * 16 + c16][32 + q4 * 8];
      }
#pragma unroll
      for (int dt = 0; dt < 4; dt++) {
        bf16x8 bv0 = *(const bf16x8*)&Vts[dt * 16 + c16][q4 * 8];
        bf16x8 bv1 = *(const bf16x8*)&Vts[dt * 16 + c16][32 + q4 * 8];
#pragma unroll
        for (int f = 0; f < 2; f++) {
          O[f][dt] = MFMA_BF16(ap[f][0], bv0, O[f][dt]);
          O[f][dt] = MFMA_BF16(ap[f][1], bv1, O[f][dt]);
        }
      }
    }
  }
#pragma unroll
  for (int f = 0; f < 2; f++) {
    float l = l_f[f];
    l += __shfl_xor(l, 16, 64);
    l += __shfl_xor(l, 32, 64);
    l_f[f] = l;
  }
  const int u = ((h * 32 + qi) * NPART + p);
  bf16* Op = Opart + (size_t)u * 8192;
#pragma unroll
  for (int f = 0; f < 2; f++)
#pragma unroll
    for (int dt = 0; dt < 4; dt++)
#pragma unroll
      for (int rg = 0; rg < 4; rg++)
        Op[(w * 32 + f * 16 + q4 * 4 + rg) * 64 + dt * 16 + c16] = (bf16)O[f][dt][rg];
  if (lane < 16) {
#pragma unroll
    for (int f = 0; f < 2; f++)
      Lpart[u * 128 + w * 32 + f * 16 + c16] = l_f[f];
  }
}

// ---------------------------------------------------------------------------
extern "C" void kernel_launch(void* const* d_in, const int* in_sizes, int n_in,
                              void* d_out, int out_size, void* d_ws, size_t ws_size,
                              hipStream_t stream)
{
  (void)in_sizes; (void)n_in; (void)out_size; (void)ws_size;
  const float* x      = (const float*)d_in[0];
  const float* qkvw   = (const float*)d_in[1];
  const float* cprojw = (const float*)d_in[2];
  float* outp = (float*)d_out;

  char* ws = (char*)d_ws;
  bf16*  xb    = (bf16*)(ws);
  bf16*  wqkv  = (bf16*)(ws + 6291456);
  bf16*  wproj = (bf16*)(ws + 9830400);
  bf16*  Q     = (bf16*)(ws + 11010048);
  bf16*  K     = (bf16*)(ws + 17301504);
  bf16*  Vt    = (bf16*)(ws + 23592960);
  bf16*  Opart = (bf16*)(ws + 29884416);
  float* Lpart = (float*)(ws + 55050240);           // total ~55.8 MB

  convert_all  <<<dim3((NX + NW + NP) / 2048),   256, 0, stream>>>(x, qkvw, cprojw, xb, wqkv, wproj);
  gemm_qkv     <<<dim3(SEQ / 128, NQKV / 128),   256, 0, stream>>>(xb, wqkv, Q, K, Vt);
  flash_partial<<<dim3(SEQ / 128, NH, NPART),    256, 0, stream>>>(Q, K, Vt, Opart, Lpart);
  gemm_proj    <<<dim3(SEQ / 128, DM / 128),     256, 0, stream>>>(Opart, Lpart, wproj, outp);
}